// Round 9
// baseline (458.640 us; speedup 1.0000x reference)
//
#include <hip/hip_runtime.h>
#include <cstdint>
#include <cstddef>

// FeatureAttention: x[4,2048,1024] fp32; Q=xWq^T+bq, K=xWk^T+bk, V=xWv^T+bv;
// out = softmax(QK^T/32) V.
//
// R9: persistent single kernel, 256 blocks x 512 threads (provably
// co-resident even if the runtime/HW treats LDS as 64KB/CU -> 1 block/CU),
// phases cvt -> QKV -> fp8 scores -> PV separated by a hand-rolled
// device-scope spin barrier (monotonic counter in ws, memset to 0 before
// launch; AGENT-scope release/acquire atomics emit the L2 writeback /
// invalidate needed for cross-XCD visibility).  R8's cooperative launch
// failed at launch time (grid=512 > conservative occupancy estimate);
// this variant depends on no launch-API validation.
// Each phase: 2 tiles per block (512 tiles total per phase).
//
// Workspace (80 MB):
//   [0,16M)  Xb bf16  [16,18) Wqb [18,20) Wkb [20,22) Wvb  (dead after P1)
//   [32,40M) Q8 fp8   [40,48M) K8 fp8   (dead after P2)
//   [48M)    barrier counter (int, zeroed via hipMemsetAsync)
//   [64,80M) Vt bf16  (V transposed [1024][8192])
//   [0,32M)  Sc bf16  (exp(scores) [4][2048][2048], reuses dead region)

typedef unsigned short ushort_t;
typedef unsigned char u8;
typedef __attribute__((ext_vector_type(4))) short short4v;
typedef __attribute__((ext_vector_type(8))) short short8;
typedef __attribute__((ext_vector_type(4))) float f32x4;

#define AS1 __attribute__((address_space(1)))
#define AS3 __attribute__((address_space(3)))

__device__ __forceinline__ ushort_t f2bf(float f) {
    unsigned int u = __float_as_uint(f);
    u += 0x7FFFu + ((u >> 16) & 1u);
    return (ushort_t)(u >> 16);
}
__device__ __forceinline__ float bf2f(ushort_t b) {
    return __uint_as_float(((unsigned)b) << 16);
}
__device__ __forceinline__ void async_ld16(const void* g, unsigned lds_off) {
    __builtin_amdgcn_global_load_lds((const AS1 void*)(uintptr_t)g,
                                     (AS3 void*)(uintptr_t)lds_off, 16, 0, 0);
}
__device__ __forceinline__ void cvt8(const float* __restrict__ s,
                                     ushort_t* __restrict__ d, size_t i) {
    const f32x4 a = *(const f32x4*)(s + i);
    const f32x4 b = *(const f32x4*)(s + i + 4);
    short8 o;
    o[0] = (short)f2bf(a[0]); o[1] = (short)f2bf(a[1]);
    o[2] = (short)f2bf(a[2]); o[3] = (short)f2bf(a[3]);
    o[4] = (short)f2bf(b[0]); o[5] = (short)f2bf(b[1]);
    o[6] = (short)f2bf(b[2]); o[7] = (short)f2bf(b[3]);
    *(short8*)(d + i) = o;
}

// grid barrier: all 256 blocks co-resident by construction.
// __syncthreads drains each wave's vmcnt (stores in L2); tid0's RELEASE
// add writes back L2; ACQUIRE loads invalidate stale L1/L2 lines.
__device__ __forceinline__ void gsync(int* bar, int target) {
    __syncthreads();
    if (threadIdx.x == 0) {
        __hip_atomic_fetch_add(bar, 1, __ATOMIC_RELEASE,
                               __HIP_MEMORY_SCOPE_AGENT);
        while (__hip_atomic_load(bar, __ATOMIC_ACQUIRE,
                                 __HIP_MEMORY_SCOPE_AGENT) < target) {
            __builtin_amdgcn_s_sleep(8);
        }
    }
    __syncthreads();
}

__global__ __launch_bounds__(512, 4) void fa_persist(
    const float* __restrict__ x,
    const float* __restrict__ Wq, const float* __restrict__ bq,
    const float* __restrict__ Wk, const float* __restrict__ bk,
    const float* __restrict__ Wv, const float* __restrict__ bv,
    float* __restrict__ out,
    ushort_t* __restrict__ Xb, ushort_t* __restrict__ Wqb,
    ushort_t* __restrict__ Wkb, ushort_t* __restrict__ Wvb,
    u8* __restrict__ Q8, u8* __restrict__ K8,
    ushort_t* __restrict__ Vt, ushort_t* __restrict__ Sc,
    int* __restrict__ bar)
{
    __shared__ __align__(16) char smem[65536];

    const int tid  = threadIdx.x;
    const int wave = tid >> 6;
    const int lane = tid & 63;
    const int blk  = blockIdx.x;          // 0..255
    const int frow = lane & 15;
    const int fg   = lane >> 4;
    const int r0   = (lane >> 4) << 2;
    const int c0   = lane & 15;

    // ================= P0: fp32 -> bf16 casts =================
    {
        const int gt = blk * 512 + tid;   // 0..131071
#pragma unroll
        for (int it = 0; it < 8; ++it)
            cvt8(x, Xb, ((size_t)gt + (size_t)it * 131072) * 8);
        cvt8(Wq, Wqb, (size_t)gt * 8);
        cvt8(Wk, Wkb, (size_t)gt * 8);
        cvt8(Wv, Wvb, (size_t)gt * 8);
    }
    gsync(bar, 256);

    // ================= P1: tri-fused QKV =================
    // 512 tiles 128x128 (by 0..63, bx 0..7); pair (b, b+256) shares bx.
    {
        ushort_t* As = (ushort_t*)smem;                 // 16 KB
        ushort_t* Bs = (ushort_t*)(smem + 16384);       // 3 x 16 KB
        const unsigned ldsA = (unsigned)(uintptr_t)As;
        const unsigned ldsB = (unsigned)(uintptr_t)Bs;
        constexpr unsigned BSTEP = 128 * 64 * 2;

        for (int ti = 0; ti < 2; ++ti) {
            const int t  = blk + ti * 256;
            const int bx = t & 7, by = t >> 3;
            const int m0 = by * 128, n0 = bx * 128;
            const int wm = (wave >> 2) * 64;
            const int wn = (wave & 3) * 32;

            const int srow = (wave << 3) + (lane >> 3);
            const int cd   = ((lane & 7) - (lane >> 3)) & 7;
            const ushort_t* gX  = Xb  + (size_t)(m0 + srow) * 1024 + cd * 8;
            const ushort_t* gW0 = Wqb + (size_t)(n0 + srow) * 1024 + cd * 8;
            const ushort_t* gW1 = Wkb + (size_t)(n0 + srow) * 1024 + cd * 8;
            const ushort_t* gW2 = Wvb + (size_t)(n0 + srow) * 1024 + cd * 8;
            const unsigned lw = (wave << 10);

            f32x4 acc[3][4][2] = {};

            for (int k0 = 0; k0 < 1024; k0 += 64) {
                __syncthreads();
#pragma unroll
                for (int c = 0; c < 2; ++c) {
                    const size_t ro = (size_t)c * 64;
                    async_ld16(gX  + ro * 1024, ldsA + c * 8192 + lw);
                    async_ld16(gW0 + ro * 1024, ldsB + 0 * BSTEP + c * 8192 + lw);
                    async_ld16(gW1 + ro * 1024, ldsB + 1 * BSTEP + c * 8192 + lw);
                    async_ld16(gW2 + ro * 1024, ldsB + 2 * BSTEP + c * 8192 + lw);
                }
                gX += 64; gW0 += 64; gW1 += 64; gW2 += 64;
                __syncthreads();

#pragma unroll
                for (int tt = 0; tt < 2; ++tt) {
                    const int ck = (tt << 2) + fg;
                    short8 af[4], bf[2];
#pragma unroll
                    for (int i = 0; i < 4; ++i) {
                        const int row = wm + i * 16 + frow;
                        af[i] = *(const short8*)&As[row * 64 + (((ck + row) & 7) << 3)];
                    }
#pragma unroll
                    for (int o = 0; o < 3; ++o) {
#pragma unroll
                        for (int j = 0; j < 2; ++j) {
                            const int row = wn + j * 16 + frow;
                            bf[j] = *(const short8*)&Bs[(size_t)o * 128 * 64 +
                                       row * 64 + (((ck + row) & 7) << 3)];
                        }
#pragma unroll
                        for (int i = 0; i < 4; ++i)
#pragma unroll
                            for (int j = 0; j < 2; ++j)
                                acc[o][i][j] = __builtin_amdgcn_mfma_f32_16x16x32_bf16(
                                    af[i], bf[j], acc[o][i][j], 0, 0, 0);
                    }
                }
            }

#pragma unroll
            for (int o = 0; o < 2; ++o) {        // Q, K -> fp8 e4m3
                u8* C = (o == 0) ? Q8 : K8;
                const float* bia = (o == 0) ? bq : bk;
#pragma unroll
                for (int i = 0; i < 4; ++i) {
#pragma unroll
                    for (int j = 0; j < 2; ++j) {
                        const int n = n0 + wn + j * 16 + c0;
                        const float bn = bia[n];
                        const int p0 = __builtin_amdgcn_cvt_pk_fp8_f32(
                            acc[o][i][j][0] + bn, acc[o][i][j][1] + bn, 0, false);
                        const int p1 = __builtin_amdgcn_cvt_pk_fp8_f32(
                            acc[o][i][j][2] + bn, acc[o][i][j][3] + bn, 0, false);
                        const size_t mb = (size_t)(m0 + wm + i * 16 + r0);
                        C[(mb + 0) * 1024 + n] = (u8)(p0 & 0xFF);
                        C[(mb + 1) * 1024 + n] = (u8)((p0 >> 8) & 0xFF);
                        C[(mb + 2) * 1024 + n] = (u8)(p1 & 0xFF);
                        C[(mb + 3) * 1024 + n] = (u8)((p1 >> 8) & 0xFF);
                    }
                }
            }
#pragma unroll
            for (int i = 0; i < 4; ++i) {        // V transposed, bf16
#pragma unroll
                for (int j = 0; j < 2; ++j) {
                    const int n = n0 + wn + j * 16 + c0;
                    const int m = m0 + wm + i * 16 + r0;
                    const float bn = bv[n];
                    short4v pk;
#pragma unroll
                    for (int r = 0; r < 4; ++r)
                        pk[r] = (short)f2bf(acc[2][i][j][r] + bn);
                    *(short4v*)&Vt[(size_t)n * 8192 + m] = pk;
                }
            }
        }
    }
    gsync(bar, 512);

    // ================= P2: Sc = exp(QK^T/32), fp8 MFMA =================
    // 512 tiles 128m x 256n (z, my 0..15, nx 0..7); pair (b, b+256).
    {
        u8* As8 = (u8*)smem;                 // 8 KB
        u8* Bs8 = (u8*)(smem + 8192);        // 16 KB
        const unsigned ldsA = (unsigned)(uintptr_t)As8;
        const unsigned ldsB = (unsigned)(uintptr_t)Bs8;

        for (int ti = 0; ti < 2; ++ti) {
            const int t  = blk + ti * 256;
            const int z  = t >> 7;
            const int rr = t & 127;
            const int m0 = (rr >> 3) * 128;
            const int n0 = (rr & 7) * 256;
            const int wm = (wave >> 2) * 64;
            const int wn = (wave & 3) * 64;

            const u8* A = Q8 + (size_t)z * 2048 * 1024;
            const u8* B = K8 + (size_t)z * 2048 * 1024;

            const int srow = (wave << 4) + (lane >> 2);
            const int cd   = ((lane & 3) - srow) & 3;
            const u8* gA = A + (size_t)(m0 + srow) * 1024 + cd * 16;
            const u8* gB = B + (size_t)(n0 + srow) * 1024 + cd * 16;
            const unsigned lw = (wave << 10);

            f32x4 acc[4][4] = {};

            for (int k0 = 0; k0 < 1024; k0 += 64) {
                __syncthreads();
                async_ld16(gA,              ldsA + lw);
                async_ld16(gB,              ldsB + lw);
                async_ld16(gB + 128 * 1024, ldsB + 8192 + lw);
                gA += 64; gB += 64;
                __syncthreads();

#pragma unroll
                for (int tt = 0; tt < 2; ++tt) {
                    const int ck = (tt << 1) + (fg >> 1);
                    const int io = (fg & 1) << 3;
                    long long af[4], bf[4];
#pragma unroll
                    for (int i = 0; i < 4; ++i) {
                        const int row = wm + i * 16 + frow;
                        af[i] = *(const long long*)&As8[row * 64 + (((ck + row) & 3) << 4) + io];
                    }
#pragma unroll
                    for (int j = 0; j < 4; ++j) {
                        const int row = wn + j * 16 + frow;
                        bf[j] = *(const long long*)&Bs8[row * 64 + (((ck + row) & 3) << 4) + io];
                    }
#pragma unroll
                    for (int i = 0; i < 4; ++i)
#pragma unroll
                        for (int j = 0; j < 4; ++j)
                            acc[i][j] = __builtin_amdgcn_mfma_f32_16x16x32_fp8_fp8(
                                af[i], bf[j], acc[i][j], 0, 0, 0);
                }
            }

            ushort_t* C = Sc + (size_t)z * 2048 * 2048;
#pragma unroll
            for (int i = 0; i < 4; ++i)
#pragma unroll
                for (int j = 0; j < 4; ++j) {
                    const int n = n0 + wn + j * 16 + c0;
#pragma unroll
                    for (int r = 0; r < 4; ++r) {
                        const int m = m0 + wm + i * 16 + r0 + r;
                        C[(size_t)m * 2048 + n] = f2bf(__expf(acc[i][j][r] * 0.03125f));
                    }
                }
        }
    }
    gsync(bar, 768);

    // ================= P3: out = (Sc Vt^T)/rowsum =================
    // 512 tiles 128x128 (z, my 0..15, nx 0..7); pair (b, b+256).
    {
        ushort_t* As = (ushort_t*)smem;                 // 16 KB
        ushort_t* Bs = (ushort_t*)(smem + 16384);       // 16 KB
        float*    rs = (float*)(smem + 32768);          // 512 B
        const unsigned ldsA = (unsigned)(uintptr_t)As;
        const unsigned ldsB = (unsigned)(uintptr_t)Bs;

        for (int ti = 0; ti < 2; ++ti) {
            const int t  = blk + ti * 256;
            const int z  = t >> 7;
            const int rr = t & 127;
            const int m0 = (rr >> 3) * 128;
            const int n0 = (rr & 7) * 128;
            const int wm = (wave >> 2) * 64;
            const int wn = (wave & 3) * 32;

            const ushort_t* A = Sc + (size_t)z * 2048 * 2048;
            const ushort_t* B = Vt + (size_t)z * 2048;

            const int srow = (wave << 3) + (lane >> 3);
            const int cd   = ((lane & 7) - (lane >> 3)) & 7;
            const ushort_t* gA = A + (size_t)(m0 + srow) * 2048 + cd * 8;
            const ushort_t* gB = B + (size_t)(n0 + srow) * 8192 + cd * 8;
            const unsigned lw = (wave << 10);

            f32x4 acc[4][2] = {};
            float rsacc[4] = {0.f, 0.f, 0.f, 0.f};

            for (int k0 = 0; k0 < 2048; k0 += 64) {
                __syncthreads();
#pragma unroll
                for (int c = 0; c < 2; ++c) {
                    const size_t ro = (size_t)c * 64;
                    async_ld16(gA + ro * 2048, ldsA + c * 8192 + lw);
                    async_ld16(gB + ro * 8192, ldsB + c * 8192 + lw);
                }
                gA += 64; gB += 64;
                __syncthreads();

#pragma unroll
                for (int tt = 0; tt < 2; ++tt) {
                    const int pa = (((tt << 2) + fg + frow) & 7) << 3;
                    short8 af[4], bf[2];
#pragma unroll
                    for (int i = 0; i < 4; ++i)
                        af[i] = *(const short8*)&As[(wm + i * 16 + frow) * 64 + pa];
                    if (wn == 0) {
#pragma unroll
                        for (int i = 0; i < 4; ++i)
#pragma unroll
                            for (int e = 0; e < 8; ++e)
                                rsacc[i] += bf2f((ushort_t)af[i][e]);
                    }
#pragma unroll
                    for (int j = 0; j < 2; ++j)
                        bf[j] = *(const short8*)&Bs[(wn + j * 16 + frow) * 64 + pa];
#pragma unroll
                    for (int i = 0; i < 4; ++i)
#pragma unroll
                        for (int j = 0; j < 2; ++j)
                            acc[i][j] = __builtin_amdgcn_mfma_f32_16x16x32_bf16(
                                af[i], bf[j], acc[i][j], 0, 0, 0);
                }
            }

            if (wn == 0) {                   // waves 0 (m 0-63), 4 (m 64-127)
#pragma unroll
                for (int i = 0; i < 4; ++i) {
                    float s = rsacc[i];
                    s += __shfl_xor(s, 16, 64);
                    s += __shfl_xor(s, 32, 64);
                    rs[wm + i * 16 + frow] = s;
                }
            }
            __syncthreads();

            float* C = out + (size_t)z * 2048 * 1024;
#pragma unroll
            for (int i = 0; i < 4; ++i) {
                float bm[4];
#pragma unroll
                for (int r = 0; r < 4; ++r)
                    bm[r] = 1.0f / rs[wm + i * 16 + r0 + r];
#pragma unroll
                for (int j = 0; j < 2; ++j) {
                    const int n = n0 + wn + j * 16 + c0;
#pragma unroll
                    for (int r = 0; r < 4; ++r) {
                        const int m = m0 + wm + i * 16 + r0 + r;
                        C[(size_t)m * 1024 + n] = acc[i][j][r] * bm[r];
                    }
                }
            }
        }
    }
}

extern "C" void kernel_launch(void* const* d_in, const int* in_sizes, int n_in,
                              void* d_out, int out_size, void* d_ws, size_t ws_size,
                              hipStream_t stream)
{
    const float* x  = (const float*)d_in[0];
    const float* Wq = (const float*)d_in[1];
    const float* bq = (const float*)d_in[2];
    const float* Wk = (const float*)d_in[3];
    const float* bk = (const float*)d_in[4];
    const float* Wv = (const float*)d_in[5];
    const float* bv = (const float*)d_in[6];
    float* out = (float*)d_out;

    char* ws = (char*)d_ws;
    const size_t MB = 1ull << 20;
    ushort_t* Xb  = (ushort_t*)(ws);
    ushort_t* Wqb = (ushort_t*)(ws + 16 * MB);
    ushort_t* Wkb = (ushort_t*)(ws + 18 * MB);
    ushort_t* Wvb = (ushort_t*)(ws + 20 * MB);
    u8*       Q8  = (u8*)(ws + 32 * MB);
    u8*       K8  = (u8*)(ws + 40 * MB);
    int*      bar = (int*)(ws + 48 * MB);
    ushort_t* Vt  = (ushort_t*)(ws + 64 * MB);
    ushort_t* Sc  = (ushort_t*)(ws);             // reuses dead Xb/W region

    hipMemsetAsync(bar, 0, sizeof(int), stream);
    fa_persist<<<dim3(256), dim3(512), 0, stream>>>(
        x, Wq, bq, Wk, bk, Wv, bv, out,
        Xb, Wqb, Wkb, Wvb, Q8, K8, Vt, Sc, bar);
}